// Round 1
// baseline (728.438 us; speedup 1.0000x reference)
//
#include <hip/hip_runtime.h>

#define BB 32
#define TT 128
#define II 256
#define HH 256
#define OO 128
#define FWID 512  // H + I

// d_ws layout: [0,4096) per-batch counters (stride 128B); [4096, 4096+65536) h double buffer
#define WS_CTR_BYTES 4096
#define WS_H_BYTES   (2 * BB * HH * 4)

__global__ __launch_bounds__(512, 2)
void stpn_kernel(const float* __restrict__ x,      // (B,T,I)
                 const float* __restrict__ wlam,   // (H,FWID)
                 const float* __restrict__ wgam,   // (H,FWID)
                 const float* __restrict__ w,      // (H,FWID)
                 const float* __restrict__ bias,   // (H)
                 const float* __restrict__ wout,   // (O,H)
                 const float* __restrict__ bout,   // (O)
                 float* __restrict__ out,          // tag(4096) | h_T(8192) | F_T(4194304)
                 unsigned* __restrict__ ctr,
                 float* __restrict__ hb0,
                 float* __restrict__ hb1)
{
    __shared__ __align__(16) float lt[FWID];

    const int tid  = threadIdx.x;
    const int bk   = blockIdx.x;
    const int b    = bk & 31;        // batch: consecutive blocks of a batch land on one XCD
    const int jg   = bk >> 5;        // j-group 0..7
    const int wv   = tid >> 6;       // wave 0..7
    const int lane = tid & 63;
    const int g    = lane >> 4;      // row group within wave, 0..3
    const int i    = lane & 15;      // lane within row group
    const int j    = jg * 32 + wv * 4 + g;   // this group's row

    unsigned* myctr = ctr + b * 32;  // 128B-strided counters

    // Per-lane f-elements of row j: f = 64*k + 4*i + c, k=0..7, c=0..3
    float4 W4[8], L4[8], G4[8], F4[8];
    {
        const float4* wr = reinterpret_cast<const float4*>(w    + j * FWID);
        const float4* lr = reinterpret_cast<const float4*>(wlam + j * FWID);
        const float4* gr = reinterpret_cast<const float4*>(wgam + j * FWID);
#pragma unroll
        for (int k = 0; k < 8; ++k) {
            W4[k] = wr[k * 16 + i];
            L4[k] = lr[k * 16 + i];
            G4[k] = gr[k * 16 + i];
            F4[k] = make_float4(0.f, 0.f, 0.f, 0.f);
        }
    }
    const float bj = bias[j];
    const float4* lt4 = reinterpret_cast<const float4*>(lt);

    float hlast = 0.f;

#pragma unroll 2
    for (int s = 0; s < TT; ++s) {
        const float* hin  = (s & 1) ? hb1 : hb0;
        float*       hout = (s & 1) ? hb0 : hb1;

        // wait for all 8 blocks of this batch to have published h for step s
        if (tid == 0) {
            const unsigned tgt = 8u * (unsigned)s;
            unsigned v = __hip_atomic_load(myctr, __ATOMIC_RELAXED, __HIP_MEMORY_SCOPE_AGENT);
            while (v < tgt) {
                __builtin_amdgcn_s_sleep(1);
                v = __hip_atomic_load(myctr, __ATOMIC_RELAXED, __HIP_MEMORY_SCOPE_AGENT);
            }
            __builtin_amdgcn_fence(__ATOMIC_ACQUIRE, "agent");
        }
        __syncthreads();

        // stage t = [x_t (256) | h (256)] into LDS
        if (tid < 256) lt[tid] = x[(b * TT + s) * II + tid];
        else           lt[tid] = hin[b * HH + (tid - 256)];
        __syncthreads();

        // per-lane t fragment (same f-mapping as W/F)
        float4 T4[8];
#pragma unroll
        for (int k = 0; k < 8; ++k) T4[k] = lt4[k * 16 + i];

        // dot = sum t*(W+F); nrm = sum (W+F)^2  -- 4 independent accumulator slots
        float4 dv = make_float4(0.f, 0.f, 0.f, 0.f);
        float4 nv = make_float4(0.f, 0.f, 0.f, 0.f);
#pragma unroll
        for (int k = 0; k < 8; ++k) {
            float twx = W4[k].x + F4[k].x;
            float twy = W4[k].y + F4[k].y;
            float twz = W4[k].z + F4[k].z;
            float tww = W4[k].w + F4[k].w;
            dv.x = fmaf(T4[k].x, twx, dv.x);
            dv.y = fmaf(T4[k].y, twy, dv.y);
            dv.z = fmaf(T4[k].z, twz, dv.z);
            dv.w = fmaf(T4[k].w, tww, dv.w);
            nv.x = fmaf(twx, twx, nv.x);
            nv.y = fmaf(twy, twy, nv.y);
            nv.z = fmaf(twz, twz, nv.z);
            nv.w = fmaf(tww, tww, nv.w);
        }
        float dot = (dv.x + dv.y) + (dv.z + dv.w);
        float nrm = (nv.x + nv.y) + (nv.z + nv.w);
        // reduce across the 16-lane row group
#pragma unroll
        for (int off = 1; off <= 8; off <<= 1) {
            dot += __shfl_xor(dot, off, 64);
            nrm += __shfl_xor(nrm, off, 64);
        }

        const float invn = 1.0f / (sqrtf(nrm) + 1e-16f);
        const float pre  = dot + bj;
        const float e    = __expf(2.0f * pre);
        const float th   = 1.0f - 2.0f / (e + 1.0f);
        const float h    = th * invn;
        hlast = h;

        if (i == 0) hout[b * HH + j] = h;
        __syncthreads();  // all waves' h stores drained (vmcnt(0) before barrier)
        if (tid == 0) {
            __hip_atomic_fetch_add(myctr, 1u, __ATOMIC_RELEASE, __HIP_MEMORY_SCOPE_AGENT);
        }

        // F update (overlaps other blocks' barrier latency)
#pragma unroll
        for (int k = 0; k < 8; ++k) {
            F4[k].x = fmaf(G4[k].x, T4[k].x * h, L4[k].x * (F4[k].x * invn));
            F4[k].y = fmaf(G4[k].y, T4[k].y * h, L4[k].y * (F4[k].y * invn));
            F4[k].z = fmaf(G4[k].z, T4[k].z * h, L4[k].z * (F4[k].z * invn));
            F4[k].w = fmaf(G4[k].w, T4[k].w * h, L4[k].w * (F4[k].w * invn));
        }
    }

    // ---- epilogue ----
    // F_T: out[12288 + (b*256 + j)*512 + f]
    {
        float4* Fo4 = reinterpret_cast<float4*>(out + 12288 + (b * HH + j) * FWID);
#pragma unroll
        for (int k = 0; k < 8; ++k) Fo4[k * 16 + i] = F4[k];
    }
    // h_T: out[4096 + b*256 + j]
    if (i == 0) out[4096 + b * HH + j] = hlast;

    // tag_space: one block per batch (jg==0), after final barrier; final h lives in hb0
    if (jg == 0) {
        if (tid == 0) {
            const unsigned tgt = 8u * (unsigned)TT;
            unsigned v = __hip_atomic_load(myctr, __ATOMIC_RELAXED, __HIP_MEMORY_SCOPE_AGENT);
            while (v < tgt) {
                __builtin_amdgcn_s_sleep(1);
                v = __hip_atomic_load(myctr, __ATOMIC_RELAXED, __HIP_MEMORY_SCOPE_AGENT);
            }
            __builtin_amdgcn_fence(__ATOMIC_ACQUIRE, "agent");
        }
        __syncthreads();
        if (tid < HH) lt[tid] = hb0[b * HH + tid];
        __syncthreads();
        if (tid < OO) {
            float acc = bout[tid];
            const float* wo = wout + tid * HH;
#pragma unroll 4
            for (int jj = 0; jj < HH; ++jj) acc = fmaf(wo[jj], lt[jj], acc);
            out[b * OO + tid] = acc;
        }
    }
}

extern "C" void kernel_launch(void* const* d_in, const int* in_sizes, int n_in,
                              void* d_out, int out_size, void* d_ws, size_t ws_size,
                              hipStream_t stream) {
    (void)in_sizes; (void)n_in; (void)out_size; (void)ws_size;
    const float* x    = (const float*)d_in[0];
    const float* wlam = (const float*)d_in[1];
    const float* wgam = (const float*)d_in[2];
    const float* w    = (const float*)d_in[3];
    const float* bias = (const float*)d_in[4];
    const float* wout = (const float*)d_in[5];
    const float* bout = (const float*)d_in[6];
    float* out = (float*)d_out;

    unsigned* ctr = (unsigned*)d_ws;
    float* hb0 = (float*)((char*)d_ws + WS_CTR_BYTES);
    float* hb1 = hb0 + BB * HH;

    // zero counters + h double buffer (d_ws is poisoned 0xAA before every launch)
    hipMemsetAsync(d_ws, 0, WS_CTR_BYTES + WS_H_BYTES, stream);

    void* args[] = {(void*)&x, (void*)&wlam, (void*)&wgam, (void*)&w, (void*)&bias,
                    (void*)&wout, (void*)&bout, (void*)&out, (void*)&ctr,
                    (void*)&hb0, (void*)&hb1};
    hipLaunchCooperativeKernel((void*)stpn_kernel, dim3(256), dim3(512), args, 0, stream);
}

// Round 2
// 622.030 us; speedup vs baseline: 1.1711x; 1.1711x over previous
//
#include <hip/hip_runtime.h>

#define BB 32
#define TT 128
#define II 256
#define HH 256
#define OO 128
#define FWID 512  // H + I

// d_ws layout: uint64 slots[2][BB][HH]  (parity, batch, row) = 128 KB.
// Slot = (stamp << 32) | float_bits(h). stamp s+1 <=> h computed at step s.
// Step s consumes stamp s from slots[s&1], publishes stamp s+1 into slots[(s+1)&1].
// Parity double-buffer + stamp chain makes overwrite formally safe:
// a producer overwrites a stamp-s slot (with stamp s+2) only after observing all
// peers at stamp s+1, which they publish only after their whole block consumed
// stamp s (poll precedes __syncthreads precedes compute/publish).

__global__ __launch_bounds__(512, 2)
void stpn_kernel(const float* __restrict__ x,      // (B,T,I)
                 const float* __restrict__ wlam,   // (H,FWID)
                 const float* __restrict__ wgam,   // (H,FWID)
                 const float* __restrict__ w,      // (H,FWID)
                 const float* __restrict__ bias,   // (H)
                 const float* __restrict__ wout,   // (O,H)
                 const float* __restrict__ bout,   // (O)
                 float* __restrict__ out,          // tag(4096) | h_T(8192) | F_T(4194304)
                 unsigned long long* __restrict__ slots)
{
    __shared__ __align__(16) float lh[2][2][HH];   // [parity][A/B][row]

    const int tid  = threadIdx.x;
    const int bk   = blockIdx.x;
    const int pr   = bk & 15;        // batch pair id -> batches pr, pr+16.
                                     // bk = pr (mod 16) => bk%8 = pr%8: all 16 blocks
                                     // of a pair land on one XCD under %8 round-robin.
    const int sl   = bk >> 4;        // row slice 0..15 (rows sl*16 .. sl*16+15)
    const int wv   = tid >> 6;       // wave 0..7
    const int lane = tid & 63;
    const int hw   = lane >> 5;      // half-wave 0/1
    const int i    = lane & 31;      // lane within half-wave
    const int r    = sl * 16 + wv * 2 + hw;   // owned row (same row for both batches)
    const int bA   = pr, bB = pr + 16;

    // poller assignment: each thread polls exactly one (batch, row) slot per step
    const int p_bt  = tid >> 8;      // 0 -> A, 1 -> B
    const int p_row = tid & 255;
    const int p_b   = p_bt ? bB : bA;

    // Per-lane f-chunks of row r: f = 128*k + 4*i + c, k=0..3, c=0..3
    float4 W4[4], L4[4], G4[4], FA[4], FB[4];
    {
        const float4* wr = reinterpret_cast<const float4*>(w    + (size_t)r * FWID);
        const float4* lr = reinterpret_cast<const float4*>(wlam + (size_t)r * FWID);
        const float4* gr = reinterpret_cast<const float4*>(wgam + (size_t)r * FWID);
#pragma unroll
        for (int k = 0; k < 4; ++k) {
            W4[k] = wr[k * 32 + i];
            L4[k] = lr[k * 32 + i];
            G4[k] = gr[k * 32 + i];
            FA[k] = make_float4(0.f, 0.f, 0.f, 0.f);
            FB[k] = make_float4(0.f, 0.f, 0.f, 0.f);
        }
    }
    const float bj = bias[r];

    float hlA = 0.f, hlB = 0.f;

    for (int s = 0; s < TT; ++s) {
        const int par = s & 1;

        // ---- poll my slot (relaxed agent atomic: no fences, sc0|sc1 load) ----
        unsigned long long* sp = slots + ((size_t)par * BB + p_b) * HH + p_row;
        unsigned long long v = __hip_atomic_load(sp, __ATOMIC_RELAXED, __HIP_MEMORY_SCOPE_AGENT);
        while ((unsigned)(v >> 32) < (unsigned)s) {
            __builtin_amdgcn_s_sleep(1);
            v = __hip_atomic_load(sp, __ATOMIC_RELAXED, __HIP_MEMORY_SCOPE_AGENT);
        }

        // x loads: independent of the poll, issue early (L2-resident)
        const float4* xA = reinterpret_cast<const float4*>(x + ((size_t)bA * TT + s) * II);
        const float4* xB = reinterpret_cast<const float4*>(x + ((size_t)bB * TT + s) * II);
        float4 TA[4], TB[4];
        TA[0] = xA[i];      TA[1] = xA[32 + i];
        TB[0] = xB[i];      TB[1] = xB[32 + i];

        lh[par][p_bt][p_row] = __uint_as_float((unsigned)v);
        __syncthreads();

        const float4* lA4 = reinterpret_cast<const float4*>(lh[par][0]);
        const float4* lB4 = reinterpret_cast<const float4*>(lh[par][1]);
        TA[2] = lA4[i];     TA[3] = lA4[32 + i];
        TB[2] = lB4[i];     TB[3] = lB4[32 + i];

        // ---- dot & norm for both batches ----
        float4 dA = make_float4(0,0,0,0), nA = make_float4(0,0,0,0);
        float4 dB = make_float4(0,0,0,0), nB = make_float4(0,0,0,0);
#pragma unroll
        for (int k = 0; k < 4; ++k) {
            float ax = W4[k].x + FA[k].x, ay = W4[k].y + FA[k].y;
            float az = W4[k].z + FA[k].z, aw = W4[k].w + FA[k].w;
            dA.x = fmaf(TA[k].x, ax, dA.x); dA.y = fmaf(TA[k].y, ay, dA.y);
            dA.z = fmaf(TA[k].z, az, dA.z); dA.w = fmaf(TA[k].w, aw, dA.w);
            nA.x = fmaf(ax, ax, nA.x); nA.y = fmaf(ay, ay, nA.y);
            nA.z = fmaf(az, az, nA.z); nA.w = fmaf(aw, aw, nA.w);
            float bx = W4[k].x + FB[k].x, by = W4[k].y + FB[k].y;
            float bz = W4[k].z + FB[k].z, bw = W4[k].w + FB[k].w;
            dB.x = fmaf(TB[k].x, bx, dB.x); dB.y = fmaf(TB[k].y, by, dB.y);
            dB.z = fmaf(TB[k].z, bz, dB.z); dB.w = fmaf(TB[k].w, bw, dB.w);
            nB.x = fmaf(bx, bx, nB.x); nB.y = fmaf(by, by, nB.y);
            nB.z = fmaf(bz, bz, nB.z); nB.w = fmaf(bw, bw, nB.w);
        }
        float dotA = (dA.x + dA.y) + (dA.z + dA.w);
        float nrmA = (nA.x + nA.y) + (nA.z + nA.w);
        float dotB = (dB.x + dB.y) + (dB.z + dB.w);
        float nrmB = (nB.x + nB.y) + (nB.z + nB.w);
#pragma unroll
        for (int off = 1; off <= 16; off <<= 1) {   // reduce within 32-lane half-wave
            dotA += __shfl_xor(dotA, off, 64);
            nrmA += __shfl_xor(nrmA, off, 64);
            dotB += __shfl_xor(dotB, off, 64);
            nrmB += __shfl_xor(nrmB, off, 64);
        }

        const float invnA = 1.0f / (sqrtf(nrmA) + 1e-16f);
        const float invnB = 1.0f / (sqrtf(nrmB) + 1e-16f);
        const float eA = __expf(2.0f * (dotA + bj));
        const float eB = __expf(2.0f * (dotB + bj));
        const float hA = (1.0f - 2.0f / (eA + 1.0f)) * invnA;
        const float hB = (1.0f - 2.0f / (eB + 1.0f)) * invnB;
        hlA = hA; hlB = hB;

        // ---- publish (fire-and-forget relaxed agent atomic stores) ----
        if (i == 0) {
            const unsigned long long st = (unsigned long long)(unsigned)(s + 1) << 32;
            unsigned long long* oA = slots + ((size_t)(par ^ 1) * BB + bA) * HH + r;
            unsigned long long* oB = slots + ((size_t)(par ^ 1) * BB + bB) * HH + r;
            __hip_atomic_store(oA, st | (unsigned)__float_as_uint(hA),
                               __ATOMIC_RELAXED, __HIP_MEMORY_SCOPE_AGENT);
            __hip_atomic_store(oB, st | (unsigned)__float_as_uint(hB),
                               __ATOMIC_RELAXED, __HIP_MEMORY_SCOPE_AGENT);
        }

        // ---- F update (overlaps peers' store propagation; next poll load
        //      is issued before its use, hiding IF latency behind this) ----
#pragma unroll
        for (int k = 0; k < 4; ++k) {
            FA[k].x = fmaf(G4[k].x, TA[k].x * hA, L4[k].x * (FA[k].x * invnA));
            FA[k].y = fmaf(G4[k].y, TA[k].y * hA, L4[k].y * (FA[k].y * invnA));
            FA[k].z = fmaf(G4[k].z, TA[k].z * hA, L4[k].z * (FA[k].z * invnA));
            FA[k].w = fmaf(G4[k].w, TA[k].w * hA, L4[k].w * (FA[k].w * invnA));
            FB[k].x = fmaf(G4[k].x, TB[k].x * hB, L4[k].x * (FB[k].x * invnB));
            FB[k].y = fmaf(G4[k].y, TB[k].y * hB, L4[k].y * (FB[k].y * invnB));
            FB[k].z = fmaf(G4[k].z, TB[k].z * hB, L4[k].z * (FB[k].z * invnB));
            FB[k].w = fmaf(G4[k].w, TB[k].w * hB, L4[k].w * (FB[k].w * invnB));
        }
    }

    // ---- epilogue: F_T and h_T from registers ----
    {
        float4* oA = reinterpret_cast<float4*>(out + 12288 + ((size_t)bA * HH + r) * FWID);
        float4* oB = reinterpret_cast<float4*>(out + 12288 + ((size_t)bB * HH + r) * FWID);
#pragma unroll
        for (int k = 0; k < 4; ++k) { oA[k * 32 + i] = FA[k]; oB[k * 32 + i] = FB[k]; }
    }
    if (i == 0) {
        out[4096 + (size_t)bA * HH + r] = hlA;
        out[4096 + (size_t)bB * HH + r] = hlB;
    }

    // ---- tag_space: slice-0 blocks only; final h has stamp TT in slots[TT&1] ----
    if (sl == 0) {
        unsigned long long* sp = slots + ((size_t)(TT & 1) * BB + p_b) * HH + p_row;
        unsigned long long v = __hip_atomic_load(sp, __ATOMIC_RELAXED, __HIP_MEMORY_SCOPE_AGENT);
        while ((unsigned)(v >> 32) < (unsigned)TT) {
            __builtin_amdgcn_s_sleep(1);
            v = __hip_atomic_load(sp, __ATOMIC_RELAXED, __HIP_MEMORY_SCOPE_AGENT);
        }
        lh[0][p_bt][p_row] = __uint_as_float((unsigned)v);
        __syncthreads();
        if (tid < 2 * OO) {
            const int bt = tid >> 7;          // 0:A 1:B
            const int o  = tid & 127;
            const float* hv = lh[0][bt];
            float acc = bout[o];
            const float* wo = wout + (size_t)o * HH;
#pragma unroll 4
            for (int jj = 0; jj < HH; ++jj) acc = fmaf(wo[jj], hv[jj], acc);
            out[(size_t)(bt ? bB : bA) * OO + o] = acc;
        }
    }
}

extern "C" void kernel_launch(void* const* d_in, const int* in_sizes, int n_in,
                              void* d_out, int out_size, void* d_ws, size_t ws_size,
                              hipStream_t stream) {
    (void)in_sizes; (void)n_in; (void)out_size; (void)ws_size;
    const float* x    = (const float*)d_in[0];
    const float* wlam = (const float*)d_in[1];
    const float* wgam = (const float*)d_in[2];
    const float* w    = (const float*)d_in[3];
    const float* bias = (const float*)d_in[4];
    const float* wout = (const float*)d_in[5];
    const float* bout = (const float*)d_in[6];
    float* out = (float*)d_out;

    unsigned long long* slots = (unsigned long long*)d_ws;

    // zero the slot buffer (stamp 0, h = 0.0 -- exactly what step 0 consumes)
    hipMemsetAsync(d_ws, 0, 2ull * BB * HH * 8ull, stream);

    void* args[] = {(void*)&x, (void*)&wlam, (void*)&wgam, (void*)&w, (void*)&bias,
                    (void*)&wout, (void*)&bout, (void*)&out, (void*)&slots};
    hipLaunchCooperativeKernel((void*)stpn_kernel, dim3(256), dim3(512), args, 0, stream);
}